// Round 1
// 702.952 us; speedup vs baseline: 1.1073x; 1.1073x over previous
//
#include <hip/hip_runtime.h>
#include <math.h>

#define N_ROWS 262144
#define KCODES 512
#define DIM 64
#define BLOCK 256              // 4 waves x 32 rows = 128 rows/block
#define ROWS_PER_BLOCK 128
#define KTILE 64               // codes staged per LDS tile (smaller => more blocks/CU)
#define NSTAGES (KCODES / KTILE)
#define LDS_ROW 72             // 64 + 8 pad bf16 elems = 144 B stride (bank-balanced)
#define PLANE_STRIDE (KTILE * LDS_ROW)   // ushorts

typedef __attribute__((ext_vector_type(8))) short short8;   // 8 bf16 = 4 VGPRs
typedef __attribute__((ext_vector_type(4))) float f4;       // MFMA accumulator / 16B vec

// Output layout (flat fp32, reference return order):
static const size_t OFF_LOSS = 0;
static const size_t OFF_Q    = 1;
static const size_t OFF_PERP = 1 + (size_t)N_ROWS * DIM;
static const size_t OFF_ENC  = OFF_PERP + 1;
static const size_t OFF_IDX  = OFF_ENC + (size_t)N_ROWS * KCODES;

__device__ __forceinline__ unsigned short bf16rne(float f) {
    unsigned int u = __float_as_uint(f);
    u = (u + 0x7fffu + ((u >> 16) & 1u)) >> 16;
    return (unsigned short)u;
}
__device__ __forceinline__ float bf16tof(unsigned short h) {
    return __uint_as_float(((unsigned int)h) << 16);
}

// Kernel 1: L2-normalize embedding rows, 3-way bf16 split into ws planes.
// x ~= h + m + l with 8 mantissa bits each => (h+m+l) matches fp32 to ~2^-26.
__global__ __launch_bounds__(64) void vq_prep(const float* __restrict__ emb,
                                              unsigned short* __restrict__ ph,
                                              unsigned short* __restrict__ pm,
                                              unsigned short* __restrict__ pl,
                                              float* __restrict__ out_loss,
                                              float* __restrict__ out_perp) {
    int k = blockIdx.x;
    int d = threadIdx.x;
    float v = emb[k * DIM + d];
    float s = v * v;
    #pragma unroll
    for (int off = 32; off > 0; off >>= 1) s += __shfl_xor(s, off, 64);
    float vn = v / fmaxf(sqrtf(s), 1e-12f);
    unsigned short h = bf16rne(vn);
    float r = vn - bf16tof(h);
    unsigned short m = bf16rne(r);
    r = r - bf16tof(m);
    unsigned short l = bf16rne(r);
    ph[k * DIM + d] = h;
    pm[k * DIM + d] = m;
    pl[k * DIM + d] = l;
    if (k == 0 && d == 0) { *out_loss = 0.0f; *out_perp = 1.0f; }
}

#define MFMA(A, B, C) C = __builtin_amdgcn_mfma_f32_16x16x32_bf16(A, B, C, 0, 0, 0)

__global__ __launch_bounds__(BLOCK, 3) void vq_main(const float* __restrict__ x,
                                                    const int* __restrict__ labels,
                                                    const float* __restrict__ emb,
                                                    const unsigned short* __restrict__ ph,
                                                    const unsigned short* __restrict__ pm,
                                                    const unsigned short* __restrict__ pl,
                                                    float* __restrict__ out_loss,
                                                    float* __restrict__ out_q,
                                                    float* __restrict__ out_enc,
                                                    float* __restrict__ out_idx) {
    const int tid   = threadIdx.x;
    const int wv    = tid >> 6;
    const int lane  = tid & 63;
    const int q     = lane >> 4;       // quad 0..3
    const int c     = lane & 15;
    const int wbase = blockIdx.x * ROWS_PER_BLOCK + wv * 32;  // wave owns 32 rows

    __shared__ __align__(16) unsigned short sE[3 * PLANE_STRIDE];  // h,m,l planes (~27 KB)
    __shared__ int   sIdx[4][32];
    __shared__ float sPick[4][32];
    __shared__ float sInv[4][32];
    __shared__ float sLoss[4];

    // ---- A fragments + per-row inverse norms + 3-way bf16 split.
    // One M-tile at a time to halve peak register pressure of the prologue.
    float inv_nx[2];
    short8 Ah[2][2], Am[2][2], Al[2][2];
    #pragma unroll
    for (int t = 0; t < 2; ++t) {
        float xv[16];
        const float* xp = x + (size_t)(wbase + t * 16 + c) * DIM + q * 8;
        #pragma unroll
        for (int s = 0; s < 2; ++s) {
            float4 lo = *(const float4*)(xp + s * 32);
            float4 hi = *(const float4*)(xp + s * 32 + 4);
            xv[s * 8 + 0] = lo.x; xv[s * 8 + 1] = lo.y;
            xv[s * 8 + 2] = lo.z; xv[s * 8 + 3] = lo.w;
            xv[s * 8 + 4] = hi.x; xv[s * 8 + 5] = hi.y;
            xv[s * 8 + 6] = hi.z; xv[s * 8 + 7] = hi.w;
        }
        float s2 = 0.f;
        #pragma unroll
        for (int j = 0; j < 16; ++j) s2 = fmaf(xv[j], xv[j], s2);
        s2 += __shfl_xor(s2, 16, 64);
        s2 += __shfl_xor(s2, 32, 64);
        inv_nx[t] = 1.0f / fmaxf(sqrtf(s2), 1e-12f);
        // 3-way bf16 split (no normalization: argmax-invariant).
        #pragma unroll
        for (int s = 0; s < 2; ++s)
            #pragma unroll
            for (int j = 0; j < 8; ++j) {
                float v = xv[s * 8 + j];
                unsigned short h = bf16rne(v);
                float r = v - bf16tof(h);
                unsigned short m = bf16rne(r);
                r = r - bf16tof(m);
                unsigned short l = bf16rne(r);
                Ah[t][s][j] = (short)h;
                Am[t][s][j] = (short)m;
                Al[t][s][j] = (short)l;
            }
    }

    // labels for this lane's 8 C-rows (rows t*16 + q*4 + r)
    int   lbl[2][4];
    float best[2][4], pick[2][4];
    int   bidx[2][4];
    #pragma unroll
    for (int t = 0; t < 2; ++t)
        #pragma unroll
        for (int r = 0; r < 4; ++r) {
            lbl[t][r]  = labels[wbase + t * 16 + q * 4 + r];
            best[t][r] = -3.4e38f;
            bidx[t][r] = 0;
            pick[t][r] = 0.f;
        }

    for (int st = 0; st < NSTAGES; ++st) {
        __syncthreads();
        // Stage 3 planes of 64 codes: 512 16B-chunks/plane, 2 per thread.
        #pragma unroll
        for (int i = 0; i < 2; ++i) {
            int ch = tid + i * BLOCK;
            int code = ch >> 3, part = ch & 7;
            int dst = code * LDS_ROW + part * 8;
            int src = st * (KTILE * DIM) + ch * 8;
            *(float4*)&sE[dst]                    = *(const float4*)(ph + src);
            *(float4*)&sE[PLANE_STRIDE + dst]     = *(const float4*)(pm + src);
            *(float4*)&sE[2 * PLANE_STRIDE + dst] = *(const float4*)(pl + src);
        }
        __syncthreads();

        #pragma unroll 2
        for (int sub = 0; sub < KTILE / 16; ++sub) {
            // B frags: lane holds code (sub*16+c), k = s*32 + q*8 + j — contiguous 16B.
            const unsigned short* bp = &sE[(sub * 16 + c) * LDS_ROW + q * 8];
            short8 Bh0 = *(const short8*)(bp);
            short8 Bh1 = *(const short8*)(bp + 32);
            short8 Bm0 = *(const short8*)(bp + PLANE_STRIDE);
            short8 Bm1 = *(const short8*)(bp + PLANE_STRIDE + 32);
            short8 Bl0 = *(const short8*)(bp + 2 * PLANE_STRIDE);
            short8 Bl1 = *(const short8*)(bp + 2 * PLANE_STRIDE + 32);

            f4 acc0 = {0.f, 0.f, 0.f, 0.f};
            f4 acc1 = {0.f, 0.f, 0.f, 0.f};
            // 6 split-products x 2 K-steps, both M-tiles (B reused 2x).
            MFMA(Ah[0][0], Bh0, acc0);  MFMA(Ah[1][0], Bh0, acc1);
            MFMA(Ah[0][1], Bh1, acc0);  MFMA(Ah[1][1], Bh1, acc1);
            MFMA(Ah[0][0], Bm0, acc0);  MFMA(Ah[1][0], Bm0, acc1);
            MFMA(Ah[0][1], Bm1, acc0);  MFMA(Ah[1][1], Bm1, acc1);
            MFMA(Am[0][0], Bh0, acc0);  MFMA(Am[1][0], Bh0, acc1);
            MFMA(Am[0][1], Bh1, acc0);  MFMA(Am[1][1], Bh1, acc1);
            MFMA(Ah[0][0], Bl0, acc0);  MFMA(Ah[1][0], Bl0, acc1);
            MFMA(Ah[0][1], Bl1, acc0);  MFMA(Ah[1][1], Bl1, acc1);
            MFMA(Al[0][0], Bh0, acc0);  MFMA(Al[1][0], Bh0, acc1);
            MFMA(Al[0][1], Bh1, acc0);  MFMA(Al[1][1], Bh1, acc1);
            MFMA(Am[0][0], Bm0, acc0);  MFMA(Am[1][0], Bm0, acc1);
            MFMA(Am[0][1], Bm1, acc0);  MFMA(Am[1][1], Bm1, acc1);

            const int code = st * KTILE + sub * 16 + c;  // this lane's column
            #pragma unroll
            for (int r = 0; r < 4; ++r) {
                float d0 = acc0[r];
                if (d0 > best[0][r]) { best[0][r] = d0; bidx[0][r] = code; }
                if (code == lbl[0][r]) pick[0][r] = d0;
                float d1 = acc1[r];
                if (d1 > best[1][r]) { best[1][r] = d1; bidx[1][r] = code; }
                if (code == lbl[1][r]) pick[1][r] = d1;
            }
        }
    }

    // Cross-lane argmax reduce within 16-lane col groups (tie -> smaller idx
    // = first max, matching jnp.argmax); pick is one-hot so sum-reduce.
    #pragma unroll
    for (int t = 0; t < 2; ++t)
        #pragma unroll
        for (int r = 0; r < 4; ++r) {
            float b = best[t][r]; int i = bidx[t][r]; float p = pick[t][r];
            #pragma unroll
            for (int m = 1; m < 16; m <<= 1) {
                float ob = __shfl_xor(b, m, 64);
                int   oi = __shfl_xor(i, m, 64);
                p += __shfl_xor(p, m, 64);
                if (ob > b || (ob == b && oi < i)) { b = ob; i = oi; }
            }
            bidx[t][r] = i; pick[t][r] = p;
        }

    if (c == 0) {
        #pragma unroll
        for (int t = 0; t < 2; ++t)
            #pragma unroll
            for (int r = 0; r < 4; ++r) {
                int rl = t * 16 + q * 4 + r;
                sIdx[wv][rl]  = bidx[t][r];
                sPick[wv][rl] = pick[t][r];
            }
    }
    if (q == 0) { sInv[wv][c] = inv_nx[0]; sInv[wv][16 + c] = inv_nx[1]; }
    __syncthreads();

    // one-hot rows: full-line coalesced 16B stores, 1.0 embedded; non-temporal
    // (537 MB stream should not thrash L2 where ph/pm/pl + x live).
    {
        const int col0 = lane * 4, col1 = 256 + lane * 4;
        for (int r = 0; r < 32; ++r) {
            int bi = sIdx[wv][r];
            float* base = out_enc + (size_t)(wbase + r) * KCODES;
            f4 v0 = { bi == col0     ? 1.f : 0.f,
                      bi == col0 + 1 ? 1.f : 0.f,
                      bi == col0 + 2 ? 1.f : 0.f,
                      bi == col0 + 3 ? 1.f : 0.f };
            __builtin_nontemporal_store(v0, (f4*)(base + col0));
            f4 v1 = { bi == col1     ? 1.f : 0.f,
                      bi == col1 + 1 ? 1.f : 0.f,
                      bi == col1 + 2 ? 1.f : 0.f,
                      bi == col1 + 3 ? 1.f : 0.f };
            __builtin_nontemporal_store(v1, (f4*)(base + col1));
        }
    }

    // quantized = raw emb row at argmax; 4 rows per pass, coalesced, nt stores.
    #pragma unroll
    for (int i = 0; i < 8; ++i) {
        int r  = i * 4 + q;
        int bi = sIdx[wv][r];
        f4 v = ((const f4*)(emb + (size_t)bi * DIM))[c];
        __builtin_nontemporal_store(v, ((f4*)(out_q + (size_t)(wbase + r) * DIM)) + c);
    }

    if (lane < 32) out_idx[wbase + lane] = (float)sIdx[wv][lane];

    // loss = mean(1 - dist[i, label_i]); dist = split-dot * inv_nx.
    float lv = 0.f;
    if (lane < 32)
        lv = (1.0f - sPick[wv][lane] * sInv[wv][lane]) * (1.0f / (float)N_ROWS);
    #pragma unroll
    for (int m = 1; m < 64; m <<= 1) lv += __shfl_xor(lv, m, 64);
    if (lane == 0) sLoss[wv] = lv;
    __syncthreads();
    if (tid == 0)
        atomicAdd(out_loss, sLoss[0] + sLoss[1] + sLoss[2] + sLoss[3]);
}

extern "C" void kernel_launch(void* const* d_in, const int* in_sizes, int n_in,
                              void* d_out, int out_size, void* d_ws, size_t ws_size,
                              hipStream_t stream) {
    const float* x      = (const float*)d_in[0];
    const int*   labels = (const int*)d_in[1];
    const float* emb    = (const float*)d_in[2];
    float* out = (float*)d_out;
    unsigned short* ph = (unsigned short*)d_ws;              // 64 KB
    unsigned short* pm = ph + (size_t)KCODES * DIM;          // 64 KB
    unsigned short* pl = pm + (size_t)KCODES * DIM;          // 64 KB (192 KB total)

    hipLaunchKernelGGL(vq_prep, dim3(KCODES), dim3(64), 0, stream,
                       emb, ph, pm, pl, out + OFF_LOSS, out + OFF_PERP);
    hipLaunchKernelGGL(vq_main, dim3(N_ROWS / ROWS_PER_BLOCK), dim3(BLOCK), 0, stream,
                       x, labels, emb, ph, pm, pl,
                       out + OFF_LOSS, out + OFF_Q, out + OFF_ENC, out + OFF_IDX);
}